// Round 1
// baseline (427.659 us; speedup 1.0000x reference)
//
#include <hip/hip_runtime.h>
#include <math.h>

typedef short bf16x8 __attribute__((ext_vector_type(8)));
typedef float f32x4  __attribute__((ext_vector_type(4)));

#define GLOAD_LDS16(SRC, DST) \
  __builtin_amdgcn_global_load_lds((const __attribute__((address_space(1))) void*)(SRC), \
      (__attribute__((address_space(3))) void*)(DST), 16, 0, 0)

__device__ __forceinline__ unsigned short f2bf(float f) {
  union { float f; unsigned u; } v; v.f = f;
  unsigned r = v.u + 0x7FFFu + ((v.u >> 16) & 1u);   // RNE
  return (unsigned short)(r >> 16);
}
__device__ __forceinline__ float bf2f(unsigned short s) {
  union { unsigned u; float f; } v; v.u = ((unsigned)s) << 16;
  return v.f;
}

// ---------------- weight conversion: W1T[j][k]=W1[k][j]; WabT[2d+p][k]=Wa/Wb[k][d]
__global__ void carp_wconv(const float* __restrict__ W1, const float* __restrict__ Wa,
                           const float* __restrict__ Wb,
                           unsigned short* __restrict__ W1T, unsigned short* __restrict__ WabT) {
  int idx = blockIdx.x * 256 + threadIdx.x;   // 0..262143 ; idx = j*512 + k
  int j = idx >> 9;
  int k = idx & 511;
  W1T[idx] = f2bf(W1[k * 512 + j]);
  int d = j >> 1;
  const float* Wx = (j & 1) ? Wb : Wa;
  WabT[idx] = f2bf(Wx[k * 256 + d]);
}

// ---------------- GEMM1: h1 = relu(h @ W1 + b1), h fp32 -> reg-staged bf16 LDS
__launch_bounds__(256)
__global__ void carp_gemm1(const float* __restrict__ h, const unsigned short* __restrict__ W1T,
                           const float* __restrict__ b1, unsigned short* __restrict__ h1) {
  __shared__ unsigned short As[128 * 32];  // [m][k] bf16, byte = m*64+2k
  __shared__ unsigned short Bs[128 * 32];  // [n][k] bf16 (W1T tile)
  int bid = blockIdx.x;
  int bn = bid & 3, bm = bid >> 2;
  int brow = bm * 128, bcol = bn * 128;
  int tid = threadIdx.x, lane = tid & 63, wid = tid >> 6;
  int wr = wid >> 1, wc = wid & 1;

  f32x4 acc[4][4] = {};

  for (int kt = 0; kt < 16; ++kt) {
    __syncthreads();                       // previous tile fully consumed
    // ---- stage A: 4 x float4 (fp32) -> cvt -> LDS bf16 (linear, byte=8*f)
    float4 av[4];
#pragma unroll
    for (int i = 0; i < 4; ++i) {
      int f = i * 256 + tid;               // float4 index; row=f>>3, col4=f&7
      int r = f >> 3, c4 = f & 7;
      av[i] = *(const float4*)(h + (size_t)(brow + r) * 512 + kt * 32 + c4 * 4);
    }
    // ---- stage B: 2 x 16B async global->LDS per thread
#pragma unroll
    for (int q = 0; q < 2; ++q) {
      int c0 = (tid >> 6) * 128 + q * 64;  // wave-uniform chunk base
      int c = c0 + lane;
      int n = c >> 2, k8 = (c & 3) * 8;
      const unsigned short* src = W1T + (size_t)(bcol + n) * 512 + kt * 32 + k8;
      GLOAD_LDS16(src, (char*)Bs + (size_t)c0 * 16);
    }
#pragma unroll
    for (int i = 0; i < 4; ++i) {
      int f = i * 256 + tid;
      ushort4 w;
      w.x = f2bf(av[i].x); w.y = f2bf(av[i].y); w.z = f2bf(av[i].z); w.w = f2bf(av[i].w);
      *(ushort4*)((char*)As + (size_t)f * 8) = w;
    }
    __syncthreads();                       // drains vmcnt+lgkmcnt
    // ---- compute: 16 MFMA
    bf16x8 afr[4], bfr[4];
#pragma unroll
    for (int m = 0; m < 4; ++m) {
      int rA = wr * 64 + m * 16 + (lane & 15);
      afr[m] = *(const bf16x8*)((const char*)As + rA * 64 + (lane >> 4) * 16);
    }
#pragma unroll
    for (int n = 0; n < 4; ++n) {
      int rB = wc * 64 + n * 16 + (lane & 15);
      bfr[n] = *(const bf16x8*)((const char*)Bs + rB * 64 + (lane >> 4) * 16);
    }
#pragma unroll
    for (int m = 0; m < 4; ++m)
#pragma unroll
      for (int n = 0; n < 4; ++n)
        acc[m][n] = __builtin_amdgcn_mfma_f32_16x16x32_bf16(afr[m], bfr[n], acc[m][n], 0, 0, 0);
  }
  // ---- epilogue: +b1, relu, bf16 store.  C map: col=lane&15, row=(lane>>4)*4+j
#pragma unroll
  for (int n = 0; n < 4; ++n) {
    int cg = bcol + wc * 64 + n * 16 + (lane & 15);
    float bias = b1[cg];
#pragma unroll
    for (int m = 0; m < 4; ++m) {
      int rbase = brow + wr * 64 + m * 16 + (lane >> 4) * 4;
#pragma unroll
      for (int j = 0; j < 4; ++j) {
        float v = acc[m][n][j] + bias;
        v = v > 0.f ? v : 0.f;
        h1[(size_t)(rbase + j) * 512 + cg] = f2bf(v);
      }
    }
  }
}

// ---------------- GEMM2: preact = h1 @ Wab_interleaved; epilogue -> per-row A partials
__launch_bounds__(256)
__global__ void carp_gemm2(const unsigned short* __restrict__ h1, const unsigned short* __restrict__ WabT,
                           const float* __restrict__ ba, const float* __restrict__ bb,
                           const float* __restrict__ Wc, float* __restrict__ A_part) {
  __shared__ unsigned short As[128 * 32];
  __shared__ unsigned short Bs[128 * 32];
  int bid = blockIdx.x;
  int bn = bid & 3, bm = bid >> 2;
  int brow = bm * 128, bcol = bn * 128;
  int tid = threadIdx.x, lane = tid & 63, wid = tid >> 6;
  int wr = wid >> 1, wc = wid & 1;

  f32x4 acc[4][4] = {};

  for (int kt = 0; kt < 16; ++kt) {
    __syncthreads();
#pragma unroll
    for (int q = 0; q < 2; ++q) {
      int c0 = (tid >> 6) * 128 + q * 64;
      int c = c0 + lane;
      int m = c >> 2, k8 = (c & 3) * 8;
      const unsigned short* srcA = h1 + (size_t)(brow + m) * 512 + kt * 32 + k8;
      GLOAD_LDS16(srcA, (char*)As + (size_t)c0 * 16);
      const unsigned short* srcB = WabT + (size_t)(bcol + m) * 512 + kt * 32 + k8;
      GLOAD_LDS16(srcB, (char*)Bs + (size_t)c0 * 16);
    }
    __syncthreads();
    bf16x8 afr[4], bfr[4];
#pragma unroll
    for (int m = 0; m < 4; ++m) {
      int rA = wr * 64 + m * 16 + (lane & 15);
      afr[m] = *(const bf16x8*)((const char*)As + rA * 64 + (lane >> 4) * 16);
    }
#pragma unroll
    for (int n = 0; n < 4; ++n) {
      int rB = wc * 64 + n * 16 + (lane & 15);
      bfr[n] = *(const bf16x8*)((const char*)Bs + rB * 64 + (lane >> 4) * 16);
    }
#pragma unroll
    for (int m = 0; m < 4; ++m)
#pragma unroll
      for (int n = 0; n < 4; ++n)
        acc[m][n] = __builtin_amdgcn_mfma_f32_16x16x32_bf16(afr[m], bfr[n], acc[m][n], 0, 0, 0);
  }
  // ---- epilogue: interleaved cols -> even lane holds a-preact, odd holds g-preact (same d)
  float rowpart[4][4] = {};                // [m][j]
#pragma unroll
  for (int n = 0; n < 4; ++n) {
    int cg = bcol + wc * 64 + n * 16 + (lane & 15);
    int d = cg >> 1;
    float bias = (cg & 1) ? bb[d] : ba[d];
    float wcd = Wc[d];
#pragma unroll
    for (int m = 0; m < 4; ++m)
#pragma unroll
      for (int j = 0; j < 4; ++j) {
        float v = acc[m][n][j] + bias;
        float av = (cg & 1) ? (1.f / (1.f + expf(-v))) : tanhf(v);
        float pv = av * __shfl_xor(av, 1, 64);   // a*g on both lanes of the pair
        rowpart[m][j] += pv * wcd;
      }
  }
  // reduce the 8 same-parity lanes of each 16-lane group (= 8 distinct d-pairs)
#pragma unroll
  for (int m = 0; m < 4; ++m)
#pragma unroll
    for (int j = 0; j < 4; ++j) {
      float t = rowpart[m][j];
      t += __shfl_xor(t, 2, 64);
      t += __shfl_xor(t, 4, 64);
      t += __shfl_xor(t, 8, 64);
      rowpart[m][j] = t;
    }
  if ((lane & 15) == 0) {
    int slot = bn * 2 + wc;
#pragma unroll
    for (int m = 0; m < 4; ++m)
#pragma unroll
      for (int j = 0; j < 4; ++j) {
        int row = brow + wr * 64 + m * 16 + (lane >> 4) * 4 + j;
        A_part[(size_t)row * 8 + slot] = rowpart[m][j];
      }
  }
}

// ---------------- per-bag: A = sum(partials)+bc ; write A_raw ; softmax -> A_sm
__global__ void carp_softmax(const float* __restrict__ A_part, const float* __restrict__ bc,
                             float* __restrict__ A_raw_out, float* __restrict__ A_sm) {
  __shared__ float sv[8192];
  __shared__ float red[256];
  int b = blockIdx.x, tid = threadIdx.x;
  float bcv = bc[0];
  float lmax = -1e30f;
  for (int i = tid; i < 8192; i += 256) {
    const float4* p = (const float4*)(A_part + (size_t)(b * 8192 + i) * 8);
    float4 x = p[0], y = p[1];
    float s = ((x.x + x.y) + (x.z + x.w)) + ((y.x + y.y) + (y.z + y.w)) + bcv;
    sv[i] = s;
    A_raw_out[b * 8192 + i] = s;
    lmax = fmaxf(lmax, s);
  }
  red[tid] = lmax;
  for (int s = 128; s > 0; s >>= 1) { __syncthreads(); if (tid < s) red[tid] = fmaxf(red[tid], red[tid + s]); }
  __syncthreads();
  float mx = red[0];
  __syncthreads();
  float lsum = 0.f;
  for (int i = tid; i < 8192; i += 256) {
    float e = expf(sv[i] - mx);
    sv[i] = e;
    lsum += e;
  }
  red[tid] = lsum;
  for (int s = 128; s > 0; s >>= 1) { __syncthreads(); if (tid < s) red[tid] += red[tid + s]; }
  __syncthreads();
  float inv = 1.f / red[0];
  for (int i = tid; i < 8192; i += 256) A_sm[b * 8192 + i] = sv[i] * inv;
}

// ---------------- M partials: Mpart[b][sp][h] = sum_{n in chunk} A_sm[b][n]*h1[b,n,h]
__global__ void carp_mkernel(const unsigned short* __restrict__ h1, const float* __restrict__ A_sm,
                             float* __restrict__ Mpart) {
  __shared__ float sw[256];
  int b = blockIdx.x >> 5, sp = blockIdx.x & 31;
  int tid = threadIdx.x;
  int n0 = sp * 256;
  sw[tid] = A_sm[b * 8192 + n0 + tid];
  __syncthreads();
  float a0 = 0.f, a1 = 0.f;
  const unsigned short* base = h1 + ((size_t)(b * 8192 + n0)) * 512 + tid * 2;
  for (int i = 0; i < 256; ++i) {
    unsigned pv = *(const unsigned*)(base + (size_t)i * 512);
    float w = sw[i];
    a0 += w * bf2f((unsigned short)(pv & 0xFFFFu));
    a1 += w * bf2f((unsigned short)(pv >> 16));
  }
  float* mp = Mpart + ((size_t)(b * 32 + sp)) * 512 + tid * 2;
  mp[0] = a0; mp[1] = a1;
}

// ---------------- final: M out, context=mean, logits, softmax, argmax
__global__ void carp_final(const float* __restrict__ Mpart, const float* __restrict__ Wcls,
                           const float* __restrict__ bcls, float* __restrict__ out) {
  __shared__ float ctx[512];
  int t = threadIdx.x;   // 512 threads
  float c = 0.f;
  for (int b = 0; b < 16; ++b) {
    float s = 0.f;
    for (int sp = 0; sp < 32; ++sp) s += Mpart[((size_t)(b * 32 + sp) << 9) + t];
    out[131077 + b * 512 + t] = s;          // M  [16,1,512]
    c += s;
  }
  ctx[t] = c * (1.f / 16.f);
  __syncthreads();
  if (t < 64) {
    float p0 = 0.f, p1 = 0.f;
    for (int hh = t; hh < 512; hh += 64) {
      float cv = ctx[hh];
      p0 += cv * Wcls[hh * 2];
      p1 += cv * Wcls[hh * 2 + 1];
    }
    for (int m = 1; m < 64; m <<= 1) { p0 += __shfl_xor(p0, m, 64); p1 += __shfl_xor(p1, m, 64); }
    if (t == 0) {
      float l0 = p0 + bcls[0], l1 = p1 + bcls[1];
      out[0] = l0; out[1] = l1;
      float mx = fmaxf(l0, l1);
      float e0 = expf(l0 - mx), e1 = expf(l1 - mx);
      float s = e0 + e1;
      out[2] = e0 / s; out[3] = e1 / s;
      out[4] = (l1 > l0) ? 1.0f : 0.0f;     // argmax (first-max tie -> 0)
    }
  }
}

extern "C" void kernel_launch(void* const* d_in, const int* in_sizes, int n_in,
                              void* d_out, int out_size, void* d_ws, size_t ws_size,
                              hipStream_t stream) {
  const float* h    = (const float*)d_in[0];
  const float* W1   = (const float*)d_in[1];
  const float* b1   = (const float*)d_in[2];
  const float* Wa   = (const float*)d_in[3];
  const float* ba   = (const float*)d_in[4];
  const float* Wb   = (const float*)d_in[5];
  const float* bb   = (const float*)d_in[6];
  const float* Wc   = (const float*)d_in[7];
  const float* bc   = (const float*)d_in[8];
  const float* Wcls = (const float*)d_in[9];
  const float* bcls = (const float*)d_in[10];
  float* out = (float*)d_out;

  char* ws = (char*)d_ws;
  unsigned short* h1   = (unsigned short*)(ws);                     // 134,217,728 B
  unsigned short* W1T  = (unsigned short*)(ws + 134217728);         //     524,288 B
  unsigned short* WabT = (unsigned short*)(ws + 134742016);         //     524,288 B
  float* A_part        = (float*)(ws + 135266304);                  //   4,194,304 B
  float* A_sm          = (float*)(ws + 139460608);                  //     524,288 B
  float* Mpart         = (float*)(ws + 139984896);                  //   1,048,576 B -> total 141,033,472 B

  carp_wconv  <<<1024, 256, 0, stream>>>(W1, Wa, Wb, W1T, WabT);
  carp_gemm1  <<<4096, 256, 0, stream>>>(h, W1T, b1, h1);
  carp_gemm2  <<<4096, 256, 0, stream>>>(h1, WabT, ba, bb, Wc, A_part);
  carp_softmax<<<16,   256, 0, stream>>>(A_part, bc, out + 5, A_sm);
  carp_mkernel<<<512,  256, 0, stream>>>(h1, A_sm, Mpart);
  carp_final  <<<1,    512, 0, stream>>>(Mpart, Wcls, bcls, out);
}